// Round 1
// baseline (408.981 us; speedup 1.0000x reference)
//
#include <hip/hip_runtime.h>
#include <math.h>

// Problem constants (from reference setup_inputs)
constexpr int BATCH = 4096;
constexpr int HID   = 512;     // I = H = O = 512
constexpr int NSTEP = 16;
constexpr int SLICE = BATCH * HID;   // 2,097,152 elements per [B,H] plane

__device__ __forceinline__ float sigmoidf_(float x) {
    return 1.0f / (1.0f + __expf(-x));
}
__device__ __forceinline__ float tanh_fast(float x) {
    x = fminf(fmaxf(x, -15.0f), 15.0f);
    float e = __expf(2.0f * x);
    return (e - 1.0f) / (e + 1.0f);
}

// Tiled f32 GEMM: out[b,n] = ACT( sum_k A[b,k] * W[k,n] + bias[n] )
// A is a virtual row-concat of up to 3 segments, each [BATCH,512] row-major.
// K = KTILES*16 (segment boundaries are multiples of 512, tiles never straddle).
// ACT: 0 = sigmoid, 1 = sigmoid * hidden (writes rh), 2 = 0.5*sigmoid,
//      3 = tanh, 4 = identity (+bias only)
template <int ACT, int KTILES>
__global__ __launch_bounds__(256)
void gemm_seg(const float* __restrict__ s0,
              const float* __restrict__ s1,
              const float* __restrict__ s2,
              const float* __restrict__ W,
              const float* __restrict__ bias,
              float* __restrict__ outp,
              const float* __restrict__ hidden)
{
    __shared__ float As[16][68];   // [k][m], pad to 68 to break power-of-2 strides
    __shared__ float Bs[16][68];   // [k][n]

    const int tid  = threadIdx.x;
    const int brow = blockIdx.x * 64;
    const int bcol = blockIdx.y * 64;
    const int ty = tid >> 4;          // 0..15
    const int tx = tid & 15;          // 0..15

    // A-load mapping: 64 rows x 16 k, float4 along k
    const int arow = tid >> 2;            // 0..63
    const int akk  = (tid & 3) << 2;      // 0,4,8,12
    // B-load mapping: 16 k x 64 n, float4 along n
    const int bkk  = tid >> 4;            // 0..15
    const int bnn  = (tid & 15) << 2;     // 0..60

    float acc[4][4] = {};

    for (int t = 0; t < KTILES; ++t) {
        const int k0 = t * 16;
        const float* seg = (k0 < 512) ? s0 : ((k0 < 1024) ? s1 : s2);
        const int kloc = k0 & 511;

        const float4 av = *(const float4*)(seg + (brow + arow) * 512 + kloc + akk);
        const float4 bv = *(const float4*)(W + (k0 + bkk) * 512 + bcol + bnn);

        As[akk + 0][arow] = av.x;
        As[akk + 1][arow] = av.y;
        As[akk + 2][arow] = av.z;
        As[akk + 3][arow] = av.w;
        *(float4*)&Bs[bkk][bnn] = bv;
        __syncthreads();

#pragma unroll
        for (int kk = 0; kk < 16; ++kk) {
            const float4 af = *(const float4*)&As[kk][ty << 2];
            const float4 bf = *(const float4*)&Bs[kk][tx << 2];
            const float a[4] = {af.x, af.y, af.z, af.w};
            const float b[4] = {bf.x, bf.y, bf.z, bf.w};
#pragma unroll
            for (int mi = 0; mi < 4; ++mi)
#pragma unroll
                for (int ni = 0; ni < 4; ++ni)
                    acc[mi][ni] = fmaf(a[mi], b[ni], acc[mi][ni]);
        }
        __syncthreads();
    }

    const float4 bb = *(const float4*)(bias + bcol + (tx << 2));
    const float bbv[4] = {bb.x, bb.y, bb.z, bb.w};

#pragma unroll
    for (int mi = 0; mi < 4; ++mi) {
        const int row = brow + (ty << 2) + mi;
        const int off = row * 512 + bcol + (tx << 2);
        float v[4];
#pragma unroll
        for (int ni = 0; ni < 4; ++ni) {
            float x = acc[mi][ni] + bbv[ni];
            if constexpr (ACT == 0 || ACT == 1) x = sigmoidf_(x);
            else if constexpr (ACT == 2)        x = 0.5f * sigmoidf_(x);
            else if constexpr (ACT == 3)        x = tanh_fast(x);
            v[ni] = x;
        }
        float4 o = {v[0], v[1], v[2], v[3]};
        if constexpr (ACT == 1) {
            const float4 hv = *(const float4*)(hidden + off);
            o.x *= hv.x; o.y *= hv.y; o.z *= hv.z; o.w *= hv.w;
        }
        *(float4*)(outp + off) = o;
    }
}

// Fused: memory filter (signed fractional-binomial weights via cumprod
// recurrence), shifted copy hiddens[1:] -> updated[0:15], and
// hidden_now = -filtered + ug*h_tilde -> updated[15].
__global__ __launch_bounds__(256)
void filter_combine(const float* __restrict__ hiddens,
                    const float* __restrict__ ug,
                    const float* __restrict__ ht,
                    const float* __restrict__ mg,
                    float* __restrict__ out_upd)
{
    const int idx = blockIdx.x * blockDim.x + threadIdx.x;   // float4 index
    const int S4 = SLICE / 4;
    const float4* h4 = (const float4*)hiddens;
    float4* o4 = (float4*)out_upd;

    const float4 d = ((const float4*)mg)[idx];
    float cx = 1.f, cy = 1.f, cz = 1.f, cw = 1.f;
    float ax = 0.f, ay = 0.f, az = 0.f, aw = 0.f;

#pragma unroll
    for (int i = 0; i < NSTEP; ++i) {
        const int j = NSTEP - 1 - i;
        const float4 v = h4[j * S4 + idx];
        const float fi = (float)i;
        const float inv = 1.0f / (float)(i + 1);
        cx *= (fi - d.x) * inv;
        cy *= (fi - d.y) * inv;
        cz *= (fi - d.z) * inv;
        cw *= (fi - d.w) * inv;
        ax = fmaf(v.x, cx, ax);
        ay = fmaf(v.y, cy, ay);
        az = fmaf(v.z, cz, az);
        aw = fmaf(v.w, cw, aw);
        if (j >= 1) o4[(j - 1) * S4 + idx] = v;
    }

    const float4 u = ((const float4*)ug)[idx];
    const float4 t = ((const float4*)ht)[idx];
    float4 hn;
    hn.x = fmaf(u.x, t.x, -ax);
    hn.y = fmaf(u.y, t.y, -ay);
    hn.z = fmaf(u.z, t.z, -az);
    hn.w = fmaf(u.w, t.w, -aw);
    o4[(NSTEP - 1) * S4 + idx] = hn;
}

extern "C" void kernel_launch(void* const* d_in, const int* in_sizes, int n_in,
                              void* d_out, int out_size, void* d_ws, size_t ws_size,
                              hipStream_t stream) {
    const float* sample   = (const float*)d_in[0];
    const float* hiddens  = (const float*)d_in[1];
    const float* mem_para = (const float*)d_in[2];
    const float* Wu = (const float*)d_in[3];
    const float* bu = (const float*)d_in[4];
    const float* Wr = (const float*)d_in[5];
    const float* br = (const float*)d_in[6];
    const float* Wm = (const float*)d_in[7];
    const float* bm = (const float*)d_in[8];
    const float* Wh = (const float*)d_in[9];
    const float* bh = (const float*)d_in[10];
    const float* Wo = (const float*)d_in[11];
    const float* bo = (const float*)d_in[12];

    float* out        = (float*)d_out;
    float* out_output = out;                        // [B,512]
    float* out_upd    = out + SLICE;                // [16,B,512]
    float* out_mg     = out + SLICE + (size_t)NSTEP * SLICE; // [B,512]

    float* ws = (float*)d_ws;
    float* ug = ws;                // [B,512]
    float* rh = ws + SLICE;        // [B,512] = reset_gate * hidden
    float* ht = ws + 2 * SLICE;    // [B,512]

    const float* hidden = hiddens + (size_t)(NSTEP - 1) * SLICE;

    dim3 grid(BATCH / 64, HID / 64);
    dim3 blk(256);

    // update_gate = sigmoid([sample,hidden] @ Wu + bu)
    gemm_seg<0, 64><<<grid, blk, 0, stream>>>(sample, hidden, nullptr, Wu, bu, ug, nullptr);
    // rh = sigmoid([sample,hidden] @ Wr + br) * hidden
    gemm_seg<1, 64><<<grid, blk, 0, stream>>>(sample, hidden, nullptr, Wr, br, rh, hidden);
    // memory_gate = 0.5*sigmoid([sample,hidden,mem_para] @ Wm + bm)  -> output #2
    gemm_seg<2, 96><<<grid, blk, 0, stream>>>(sample, hidden, mem_para, Wm, bm, out_mg, nullptr);
    // h_tilde = tanh([sample, rh] @ Wh + bh)
    gemm_seg<3, 64><<<grid, blk, 0, stream>>>(sample, rh, nullptr, Wh, bh, ht, nullptr);
    // filter + shifted copy + hidden_now -> updated_hiddens
    filter_combine<<<dim3(SLICE / 4 / 256), blk, 0, stream>>>(hiddens, ug, ht, out_mg, out_upd);
    // output = hidden_now @ Wo + bo -> output #0
    gemm_seg<4, 32><<<grid, blk, 0, stream>>>(out_upd + (size_t)(NSTEP - 1) * SLICE,
                                              nullptr, nullptr, Wo, bo, out_output, nullptr);
}

// Round 3
// 161.467 us; speedup vs baseline: 2.5329x; 2.5329x over previous
//
#include <hip/hip_runtime.h>
#include <math.h>

typedef __bf16 bf16;
typedef __bf16 bf16x8 __attribute__((ext_vector_type(8)));
typedef __bf16 bf16x4 __attribute__((ext_vector_type(4)));
typedef float  f32x4  __attribute__((ext_vector_type(4)));

constexpr int BATCH = 4096;
constexpr int HID   = 512;
constexpr int NSTEP = 16;
constexpr int SLICE = BATCH * HID;   // elements per [B,H] plane

__device__ __forceinline__ float sigmoidf_(float x) {
    return 1.0f / (1.0f + __expf(-x));
}
__device__ __forceinline__ float tanh_fast(float x) {
    x = fminf(fmaxf(x, -15.0f), 15.0f);
    float e = __expf(2.0f * x);
    return (e - 1.0f) / (e + 1.0f);
}

__device__ __forceinline__ void gload_lds16(const void* g, void* l) {
    __builtin_amdgcn_global_load_lds((const __attribute__((address_space(1))) void*)g,
                                     (__attribute__((address_space(3))) void*)l,
                                     16, 0, 0);
}

// ---------------------------------------------------------------------------
// f32 -> bf16 elementwise convert (vectorized: float4 in, 4x bf16 out)
__global__ __launch_bounds__(256)
void convert_bf16(const float* __restrict__ in, bf16* __restrict__ out, int n4) {
    int i = blockIdx.x * blockDim.x + threadIdx.x;
    if (i < n4) {
        float4 v = ((const float4*)in)[i];
        bf16x4 o = {(bf16)v.x, (bf16)v.y, (bf16)v.z, (bf16)v.w};
        ((bf16x4*)out)[i] = o;
    }
}

// ---------------------------------------------------------------------------
// Tiled transpose+convert: out[(row_off + c)*out_stride + r] = (bf16) in[r][c]
// in: [R][C] f32 row-major. R, C multiples of 32.
__global__ __launch_bounds__(256)
void transpose_f32_bf16(const float* __restrict__ in, int R, int C,
                        bf16* __restrict__ out, int out_stride, int row_off) {
    __shared__ float tile[32][33];
    const int r0 = blockIdx.x * 32, c0 = blockIdx.y * 32;
    const int tr = threadIdx.x >> 5;   // 0..7
    const int tc = threadIdx.x & 31;   // 0..31
#pragma unroll
    for (int i = 0; i < 4; ++i)
        tile[tr + i * 8][tc] = in[(size_t)(r0 + tr + i * 8) * C + c0 + tc];
    __syncthreads();
#pragma unroll
    for (int i = 0; i < 4; ++i) {
        const int c = tr + i * 8;
        out[(size_t)(row_off + c0 + c) * out_stride + r0 + tc] = (bf16)tile[tc][c];
    }
}

// ---------------------------------------------------------------------------
// MFMA GEMM: out[b,n] = ACT( sum_k A[b,k] * W[k,n] + bias[n] )
// A: virtual row-concat of up to 3 bf16 segments, each [BATCH,512] row-major.
// Wt: B^T layout, bf16 [N_total][K_total] row-major (ldK = K_total).
// Tile: BM=128, BN=64, BK=64; 256 threads = 4 waves (2x2), wave tile 64x32.
// LDS: linear dest for global_load_lds, XOR-swizzled SOURCE, swizzled READ
// (rule 21: both-sides-or-neither; swizzle = chunk ^ (row&7), 16B chunks).
// ACT: 0 = fused U|R (col<512: ug=sigmoid -> bf16 outA;
//                     col>=512: rh=sigmoid*hidden -> bf16 outB)
//      1 = 0.5*sigmoid -> f32 outA
//      2 = tanh -> bf16 outA
//      3 = identity (+bias) -> f32 outA
template <int ACT, int KTILES>
__global__ __launch_bounds__(256)
void gemm_mfma(const bf16* __restrict__ segA0,
               const bf16* __restrict__ segA1,
               const bf16* __restrict__ segA2,
               const bf16* __restrict__ Wt, int ldK,
               const float* __restrict__ bias0,
               const float* __restrict__ bias1,
               void* __restrict__ outA,
               void* __restrict__ outB,
               const float* __restrict__ hidden) {
    __shared__ bf16 As[128 * 64];   // [row][chunk*8]  (16KB)
    __shared__ bf16 Bs[64 * 64];    // [n][chunk*8]    (8KB)

    const int tid  = threadIdx.x;
    const int wid  = tid >> 6;
    const int lane = tid & 63;
    const int wr = wid >> 1, wc = wid & 1;
    const int brow = blockIdx.x * 128;
    const int bcol = blockIdx.y * 64;

    const bf16* segs[3] = {segA0, segA1, segA2};

    const int s_row  = tid >> 3;   // 0..31 (plus c*32)
    const int s_chnk = tid & 7;    // 16B chunk within 128B row

    f32x4 acc[4][2] = {};

    for (int t = 0; t < KTILES; ++t) {
        const int k0 = t * 64;
        const bf16* Aseg = segs[k0 >> 9];
        const int kloc = k0 & 511;

        // ---- stage A: 4 calls x (4 waves x 64 lanes x 16B) = 16KB
#pragma unroll
        for (int c = 0; c < 4; ++c) {
            const int row = c * 32 + s_row;
            const int sc  = s_chnk ^ (row & 7);      // inverse-swizzled source
            const bf16* src = Aseg + (size_t)(brow + row) * 512 + kloc + sc * 8;
            bf16* ldst = As + (size_t)(c * 256 + (wid << 6)) * 8;  // wave-uniform
            gload_lds16(src, ldst);
        }
        // ---- stage B^T: 2 calls = 8KB
#pragma unroll
        for (int c = 0; c < 2; ++c) {
            const int row = c * 32 + s_row;
            const int sc  = s_chnk ^ (row & 7);
            const bf16* src = Wt + (size_t)(bcol + row) * ldK + k0 + sc * 8;
            bf16* ldst = Bs + (size_t)(c * 256 + (wid << 6)) * 8;
            gload_lds16(src, ldst);
        }
        __syncthreads();

        // ---- compute: 2 k-steps of 32, 4x2 fragments
#pragma unroll
        for (int ks = 0; ks < 2; ++ks) {
            const int kb = ks * 64 + ((lane >> 4) << 4);  // k byte-offset in row
            bf16x8 bfrag[2];
#pragma unroll
            for (int ni = 0; ni < 2; ++ni) {
                const int n = wc * 32 + ni * 16 + (lane & 15);
                const int byte = n * 128 + (kb ^ ((n & 7) << 4));  // swizzled read
                bfrag[ni] = *(const bf16x8*)((const char*)Bs + byte);
            }
#pragma unroll
            for (int mi = 0; mi < 4; ++mi) {
                const int m = wr * 64 + mi * 16 + (lane & 15);
                const int byte = m * 128 + (kb ^ ((m & 7) << 4));
                const bf16x8 afrag = *(const bf16x8*)((const char*)As + byte);
#pragma unroll
                for (int ni = 0; ni < 2; ++ni)
                    acc[mi][ni] = __builtin_amdgcn_mfma_f32_16x16x32_bf16(
                        afrag, bfrag[ni], acc[mi][ni], 0, 0, 0);
            }
        }
        __syncthreads();
    }

    // ---- epilogue: C/D mapping col=lane&15, row=(lane>>4)*4+reg (m89)
    const int lr4 = (lane >> 4) * 4;
    const int lc  = lane & 15;
#pragma unroll
    for (int mi = 0; mi < 4; ++mi) {
#pragma unroll
        for (int ni = 0; ni < 2; ++ni) {
            const int col = bcol + wc * 32 + ni * 16 + lc;
            const f32x4 a = acc[mi][ni];
#pragma unroll
            for (int r = 0; r < 4; ++r) {
                const int row = brow + wr * 64 + mi * 16 + lr4 + r;
                const float x = a[r];
                if constexpr (ACT == 0) {
                    if (col < 512) {
                        const float v = sigmoidf_(x + bias0[col]);
                        ((bf16*)outA)[(size_t)row * 512 + col] = (bf16)v;
                    } else {
                        const int c2 = col - 512;
                        const float v = sigmoidf_(x + bias1[c2]) *
                                        hidden[(size_t)row * 512 + c2];
                        ((bf16*)outB)[(size_t)row * 512 + c2] = (bf16)v;
                    }
                } else if constexpr (ACT == 1) {
                    ((float*)outA)[(size_t)row * 512 + col] =
                        0.5f * sigmoidf_(x + bias0[col]);
                } else if constexpr (ACT == 2) {
                    ((bf16*)outA)[(size_t)row * 512 + col] = (bf16)tanh_fast(x + bias0[col]);
                } else {
                    ((float*)outA)[(size_t)row * 512 + col] = x + bias0[col];
                }
            }
        }
    }
}

// ---------------------------------------------------------------------------
// Fused memory filter + shifted copy + hidden_now (f32 out + bf16 copy)
__global__ __launch_bounds__(256)
void filter_combine(const float* __restrict__ hiddens,
                    const bf16* __restrict__ ugb,
                    const bf16* __restrict__ htb,
                    const float* __restrict__ mg,
                    float* __restrict__ out_upd,
                    bf16* __restrict__ hnb) {
    const int idx = blockIdx.x * blockDim.x + threadIdx.x;   // float4 index
    const int S4 = SLICE / 4;
    const float4* h4 = (const float4*)hiddens;
    float4* o4 = (float4*)out_upd;

    const float4 d = ((const float4*)mg)[idx];
    float cx = 1.f, cy = 1.f, cz = 1.f, cw = 1.f;
    float ax = 0.f, ay = 0.f, az = 0.f, aw = 0.f;

#pragma unroll
    for (int i = 0; i < NSTEP; ++i) {
        const int j = NSTEP - 1 - i;
        const float4 v = h4[j * S4 + idx];
        const float fi = (float)i;
        const float inv = 1.0f / (float)(i + 1);
        cx *= (fi - d.x) * inv;
        cy *= (fi - d.y) * inv;
        cz *= (fi - d.z) * inv;
        cw *= (fi - d.w) * inv;
        ax = fmaf(v.x, cx, ax);
        ay = fmaf(v.y, cy, ay);
        az = fmaf(v.z, cz, az);
        aw = fmaf(v.w, cw, aw);
        if (j >= 1) o4[(j - 1) * S4 + idx] = v;
    }

    const bf16x4 u4 = ((const bf16x4*)ugb)[idx];
    const bf16x4 t4 = ((const bf16x4*)htb)[idx];
    float4 hn;
    hn.x = fmaf((float)u4[0], (float)t4[0], -ax);
    hn.y = fmaf((float)u4[1], (float)t4[1], -ay);
    hn.z = fmaf((float)u4[2], (float)t4[2], -az);
    hn.w = fmaf((float)u4[3], (float)t4[3], -aw);
    o4[(NSTEP - 1) * S4 + idx] = hn;
    bf16x4 hb = {(bf16)hn.x, (bf16)hn.y, (bf16)hn.z, (bf16)hn.w};
    ((bf16x4*)hnb)[idx] = hb;
}

// ---------------------------------------------------------------------------
extern "C" void kernel_launch(void* const* d_in, const int* in_sizes, int n_in,
                              void* d_out, int out_size, void* d_ws, size_t ws_size,
                              hipStream_t stream) {
    const float* sample   = (const float*)d_in[0];
    const float* hiddens  = (const float*)d_in[1];
    const float* mem_para = (const float*)d_in[2];
    const float* Wu = (const float*)d_in[3];
    const float* bu = (const float*)d_in[4];
    const float* Wr = (const float*)d_in[5];
    const float* br = (const float*)d_in[6];
    const float* Wm = (const float*)d_in[7];
    const float* bm = (const float*)d_in[8];
    const float* Wh = (const float*)d_in[9];
    const float* bh = (const float*)d_in[10];
    const float* Wo = (const float*)d_in[11];
    const float* bo = (const float*)d_in[12];

    float* out        = (float*)d_out;
    float* out_output = out;                                  // [B,512]
    float* out_upd    = out + SLICE;                          // [16,B,512]
    float* out_mg     = out + SLICE + (size_t)NSTEP * SLICE;  // [B,512]

    const float* hidden = hiddens + (size_t)(NSTEP - 1) * SLICE;

    // workspace layout (bf16 unless noted); 4MB chunks
    char* ws = (char*)d_ws;
    bf16* Sb    = (bf16*)(ws);                          // sample
    bf16* Hb    = (bf16*)(ws + (((size_t) 4) << 20));   // hidden
    bf16* Mb    = (bf16*)(ws + (((size_t) 8) << 20));   // mem_para
    bf16* RHb   = (bf16*)(ws + (((size_t)12) << 20));   // reset_gate*hidden
    bf16* HNb   = (bf16*)(ws + (((size_t)16) << 20));   // hidden_now
    bf16* UGb   = (bf16*)(ws + (((size_t)20) << 20));   // update_gate
    bf16* HTb   = (bf16*)(ws + (((size_t)24) << 20));   // h_tilde
    bf16* Wur_t = (bf16*)(ws + (((size_t)28) << 20));   // [1024][1024]
    bf16* Wm_t  = (bf16*)(ws + (((size_t)31) << 20));   // [512][1536]
    bf16* Wh_t  = (bf16*)(ws + (((size_t)33) << 20));   // [512][1024]
    bf16* Wo_t  = (bf16*)(ws + (((size_t)35) << 20));   // [512][512]

    dim3 blk(256);
    const int n4 = SLICE / 4;

    // 1. convert A-side operands to bf16
    convert_bf16<<<n4 / 256, blk, 0, stream>>>(sample,   Sb, n4);
    convert_bf16<<<n4 / 256, blk, 0, stream>>>(hidden,   Hb, n4);
    convert_bf16<<<n4 / 256, blk, 0, stream>>>(mem_para, Mb, n4);

    // 2. transpose-convert weights to B^T bf16 [N][K]
    transpose_f32_bf16<<<dim3(32, 16), blk, 0, stream>>>(Wu, 1024, 512, Wur_t, 1024, 0);
    transpose_f32_bf16<<<dim3(32, 16), blk, 0, stream>>>(Wr, 1024, 512, Wur_t, 1024, 512);
    transpose_f32_bf16<<<dim3(48, 16), blk, 0, stream>>>(Wm, 1536, 512, Wm_t, 1536, 0);
    transpose_f32_bf16<<<dim3(32, 16), blk, 0, stream>>>(Wh, 1024, 512, Wh_t, 1024, 0);
    transpose_f32_bf16<<<dim3(16, 16), blk, 0, stream>>>(Wo,  512, 512, Wo_t,  512, 0);

    // 3. fused update|reset gates: N=1024, K=1024 -> UGb, RHb
    gemm_mfma<0, 16><<<dim3(32, 16), blk, 0, stream>>>(
        Sb, Hb, nullptr, Wur_t, 1024, bu, br, UGb, RHb, hidden);
    // 4. memory gate: N=512, K=1536 -> out_mg (f32 output)
    gemm_mfma<1, 24><<<dim3(32, 8), blk, 0, stream>>>(
        Sb, Hb, Mb, Wm_t, 1536, bm, nullptr, out_mg, nullptr, nullptr);
    // 5. h_tilde: N=512, K=1024 -> HTb
    gemm_mfma<2, 16><<<dim3(32, 8), blk, 0, stream>>>(
        Sb, RHb, nullptr, Wh_t, 1024, bh, nullptr, HTb, nullptr, nullptr);
    // 6. filter + shifted copy + hidden_now
    filter_combine<<<n4 / 256, blk, 0, stream>>>(hiddens, UGb, HTb, out_mg, out_upd, HNb);
    // 7. output = hidden_now @ Wo + bo: N=512, K=512 -> out_output (f32)
    gemm_mfma<3, 8><<<dim3(32, 8), blk, 0, stream>>>(
        HNb, nullptr, nullptr, Wo_t, 512, bo, nullptr, out_output, nullptr, nullptr);
}

// Round 4
// 135.924 us; speedup vs baseline: 3.0089x; 1.1879x over previous
//
#include <hip/hip_runtime.h>
#include <math.h>

typedef __bf16 bf16;
typedef __bf16 bf16x8 __attribute__((ext_vector_type(8)));
typedef __bf16 bf16x4 __attribute__((ext_vector_type(4)));
typedef float  f32x4  __attribute__((ext_vector_type(4)));

constexpr int BATCH = 4096;
constexpr int HID   = 512;
constexpr int NSTEP = 16;
constexpr int SLICE = BATCH * HID;   // elements per [B,H] plane

__device__ __forceinline__ float sigmoidf_(float x) {
    return 1.0f / (1.0f + __expf(-x));
}
__device__ __forceinline__ float tanh_fast(float x) {
    x = fminf(fmaxf(x, -15.0f), 15.0f);
    float e = __expf(2.0f * x);
    return (e - 1.0f) / (e + 1.0f);
}

__device__ __forceinline__ void gload_lds16(const void* g, void* l) {
    __builtin_amdgcn_global_load_lds((const __attribute__((address_space(1))) void*)g,
                                     (__attribute__((address_space(3))) void*)l,
                                     16, 0, 0);
}

// ---------------------------------------------------------------------------
// Fused prep: convert sample/hidden/mem_para to bf16 + zero-fill the K-pad
// region of Wall_t (rows 0..1023, k 1024..1535).
__global__ __launch_bounds__(256)
void prep_data(const float* __restrict__ sample,
               const float* __restrict__ hidden,
               const float* __restrict__ mem_para,
               bf16* __restrict__ Sb, bf16* __restrict__ Hb, bf16* __restrict__ Mb,
               bf16* __restrict__ Wall_t) {
    const int bid = blockIdx.x;
    const int tid = threadIdx.x;
    if (bid < 6144) {
        const int seg = bid >> 11;              // 0,1,2
        const int i = (bid & 2047) * 256 + tid; // float4 index, < SLICE/4
        const float* in = (seg == 0) ? sample : (seg == 1) ? hidden : mem_para;
        bf16* out = (seg == 0) ? Sb : (seg == 1) ? Hb : Mb;
        float4 v = ((const float4*)in)[i];
        bf16x4 o = {(bf16)v.x, (bf16)v.y, (bf16)v.z, (bf16)v.w};
        ((bf16x4*)out)[i] = o;
    } else {
        // zero pad: 1024 rows x 512 bf16 = 65536 chunks of 8 bf16
        const int c = (bid - 6144) * 256 + tid;
        const int row = c >> 6;
        const int off = (c & 63) * 8;
        bf16x8 z = {};
        *(bf16x8*)(Wall_t + (size_t)row * 1536 + 1024 + off) = z;
    }
}

// ---------------------------------------------------------------------------
// All weight transposes in one kernel. Each block does one 32x32 tile:
// out[(row_off + c)*stride + r] = (bf16) in[r][c]
__global__ __launch_bounds__(256)
void prep_weights(const float* __restrict__ Wu, const float* __restrict__ Wr,
                  const float* __restrict__ Wm, const float* __restrict__ Wh,
                  const float* __restrict__ Wo,
                  bf16* __restrict__ Wall_t, bf16* __restrict__ Wh_t,
                  bf16* __restrict__ Wo_t) {
    __shared__ float tile[32][33];
    const int t = blockIdx.x;
    const float* in; bf16* out; int C, stride, row_off, rt, ct;
    if (t < 512)        { in = Wu; out = Wall_t; C = 512; stride = 1536; row_off = 0;
                          rt = t >> 4; ct = t & 15; }
    else if (t < 1024)  { in = Wr; out = Wall_t; C = 512; stride = 1536; row_off = 512;
                          int t2 = t - 512;  rt = t2 >> 4; ct = t2 & 15; }
    else if (t < 1792)  { in = Wm; out = Wall_t; C = 512; stride = 1536; row_off = 1024;
                          int t2 = t - 1024; rt = t2 >> 4; ct = t2 & 15; }
    else if (t < 2304)  { in = Wh; out = Wh_t;   C = 512; stride = 1024; row_off = 0;
                          int t2 = t - 1792; rt = t2 >> 4; ct = t2 & 15; }
    else                { in = Wo; out = Wo_t;   C = 512; stride = 512;  row_off = 0;
                          int t2 = t - 2304; rt = t2 >> 4; ct = t2 & 15; }
    const int r0 = rt * 32, c0 = ct * 32;
    const int tr = threadIdx.x >> 5;   // 0..7
    const int tc = threadIdx.x & 31;   // 0..31
#pragma unroll
    for (int i = 0; i < 4; ++i)
        tile[tr + i * 8][tc] = in[(size_t)(r0 + tr + i * 8) * C + c0 + tc];
    __syncthreads();
#pragma unroll
    for (int i = 0; i < 4; ++i) {
        const int c = tr + i * 8;
        out[(size_t)(row_off + c0 + c) * stride + r0 + tc] = (bf16)tile[tc][c];
    }
}

// ---------------------------------------------------------------------------
// MFMA GEMM: out[b,n] = ACT( sum_k A[b,k] * W[k,n] + bias[n] )
// A: virtual row-concat of up to 3 bf16 segments, each [BATCH,512] row-major.
// Wt: B^T layout, bf16 [N_total][K_total] row-major (ldK = K_total).
// Tile: BM=128, BN=64, BK=64; 256 threads = 4 waves (2x2), wave tile 64x32.
// LDS: linear dest for global_load_lds, XOR-pre-swizzled SOURCE, swizzled READ.
// ACT: 0 = fused U|R|M (col<512: ug=sigmoid -> bf16 outA;
//                       512<=col<1024: rh=sigmoid*hb -> bf16 outB;
//                       col>=1024: mg=0.5*sigmoid -> f32 outC)
//      2 = tanh -> bf16 outA
//      3 = identity (+bias) -> f32 outA
template <int ACT, int KTILES>
__global__ __launch_bounds__(256)
void gemm_mfma(const bf16* __restrict__ segA0,
               const bf16* __restrict__ segA1,
               const bf16* __restrict__ segA2,
               const bf16* __restrict__ Wt, int ldK,
               const float* __restrict__ b0,
               const float* __restrict__ b1,
               const float* __restrict__ b2,
               void* __restrict__ outA,
               void* __restrict__ outB,
               void* __restrict__ outC,
               const bf16* __restrict__ hiddenb) {
    __shared__ bf16 As[128 * 64];   // 16KB
    __shared__ bf16 Bs[64 * 64];    // 8KB

    const int tid  = threadIdx.x;
    const int wid  = tid >> 6;
    const int lane = tid & 63;
    const int wr = wid >> 1, wc = wid & 1;
    const int brow = blockIdx.x * 128;
    const int bcol = blockIdx.y * 64;

    const bf16* segs[3] = {segA0, segA1, segA2};

    const int s_row  = tid >> 3;   // 0..31 (plus c*32)
    const int s_chnk = tid & 7;    // 16B chunk within 128B row

    f32x4 acc[4][2] = {};

    for (int t = 0; t < KTILES; ++t) {
        const int k0 = t * 64;
        const bf16* Aseg = segs[k0 >> 9];
        const int kloc = k0 & 511;

#pragma unroll
        for (int c = 0; c < 4; ++c) {
            const int row = c * 32 + s_row;
            const int sc  = s_chnk ^ (row & 7);
            const bf16* src = Aseg + (size_t)(brow + row) * 512 + kloc + sc * 8;
            bf16* ldst = As + (size_t)(c * 256 + (wid << 6)) * 8;
            gload_lds16(src, ldst);
        }
#pragma unroll
        for (int c = 0; c < 2; ++c) {
            const int row = c * 32 + s_row;
            const int sc  = s_chnk ^ (row & 7);
            const bf16* src = Wt + (size_t)(bcol + row) * ldK + k0 + sc * 8;
            bf16* ldst = Bs + (size_t)(c * 256 + (wid << 6)) * 8;
            gload_lds16(src, ldst);
        }
        __syncthreads();

#pragma unroll
        for (int ks = 0; ks < 2; ++ks) {
            const int kb = ks * 64 + ((lane >> 4) << 4);
            bf16x8 bfrag[2];
#pragma unroll
            for (int ni = 0; ni < 2; ++ni) {
                const int n = wc * 32 + ni * 16 + (lane & 15);
                const int byte = n * 128 + (kb ^ ((n & 7) << 4));
                bfrag[ni] = *(const bf16x8*)((const char*)Bs + byte);
            }
#pragma unroll
            for (int mi = 0; mi < 4; ++mi) {
                const int m = wr * 64 + mi * 16 + (lane & 15);
                const int byte = m * 128 + (kb ^ ((m & 7) << 4));
                const bf16x8 afrag = *(const bf16x8*)((const char*)As + byte);
#pragma unroll
                for (int ni = 0; ni < 2; ++ni)
                    acc[mi][ni] = __builtin_amdgcn_mfma_f32_16x16x32_bf16(
                        afrag, bfrag[ni], acc[mi][ni], 0, 0, 0);
            }
        }
        __syncthreads();
    }

    // epilogue: C/D mapping col=lane&15, row=(lane>>4)*4+reg (m89)
    const int lr4 = (lane >> 4) * 4;
    const int lc  = lane & 15;
#pragma unroll
    for (int mi = 0; mi < 4; ++mi) {
#pragma unroll
        for (int ni = 0; ni < 2; ++ni) {
            const int col = bcol + wc * 32 + ni * 16 + lc;
            const f32x4 a = acc[mi][ni];
#pragma unroll
            for (int r = 0; r < 4; ++r) {
                const int row = brow + wr * 64 + mi * 16 + lr4 + r;
                const float x = a[r];
                if constexpr (ACT == 0) {
                    if (col < 512) {
                        const float v = sigmoidf_(x + b0[col]);
                        ((bf16*)outA)[(size_t)row * 512 + col] = (bf16)v;
                    } else if (col < 1024) {
                        const int c2 = col - 512;
                        const float v = sigmoidf_(x + b1[c2]) *
                                        (float)hiddenb[(size_t)row * 512 + c2];
                        ((bf16*)outB)[(size_t)row * 512 + c2] = (bf16)v;
                    } else {
                        const int c3 = col - 1024;
                        ((float*)outC)[(size_t)row * 512 + c3] =
                            0.5f * sigmoidf_(x + b2[c3]);
                    }
                } else if constexpr (ACT == 2) {
                    ((bf16*)outA)[(size_t)row * 512 + col] = (bf16)tanh_fast(x + b0[col]);
                } else {
                    ((float*)outA)[(size_t)row * 512 + col] = x + b0[col];
                }
            }
        }
    }
}

// ---------------------------------------------------------------------------
// Fused memory filter + shifted copy + hidden_now (f32 out + bf16 copy)
__global__ __launch_bounds__(256)
void filter_combine(const float* __restrict__ hiddens,
                    const bf16* __restrict__ ugb,
                    const bf16* __restrict__ htb,
                    const float* __restrict__ mg,
                    float* __restrict__ out_upd,
                    bf16* __restrict__ hnb) {
    const int idx = blockIdx.x * blockDim.x + threadIdx.x;   // float4 index
    const int S4 = SLICE / 4;
    const float4* h4 = (const float4*)hiddens;
    float4* o4 = (float4*)out_upd;

    const float4 d = ((const float4*)mg)[idx];
    float cx = 1.f, cy = 1.f, cz = 1.f, cw = 1.f;
    float ax = 0.f, ay = 0.f, az = 0.f, aw = 0.f;

#pragma unroll
    for (int i = 0; i < NSTEP; ++i) {
        const int j = NSTEP - 1 - i;
        const float4 v = h4[j * S4 + idx];
        const float fi = (float)i;
        const float inv = 1.0f / (float)(i + 1);
        cx *= (fi - d.x) * inv;
        cy *= (fi - d.y) * inv;
        cz *= (fi - d.z) * inv;
        cw *= (fi - d.w) * inv;
        ax = fmaf(v.x, cx, ax);
        ay = fmaf(v.y, cy, ay);
        az = fmaf(v.z, cz, az);
        aw = fmaf(v.w, cw, aw);
        if (j >= 1) o4[(j - 1) * S4 + idx] = v;
    }

    const bf16x4 u4 = ((const bf16x4*)ugb)[idx];
    const bf16x4 t4 = ((const bf16x4*)htb)[idx];
    float4 hn;
    hn.x = fmaf((float)u4[0], (float)t4[0], -ax);
    hn.y = fmaf((float)u4[1], (float)t4[1], -ay);
    hn.z = fmaf((float)u4[2], (float)t4[2], -az);
    hn.w = fmaf((float)u4[3], (float)t4[3], -aw);
    o4[(NSTEP - 1) * S4 + idx] = hn;
    bf16x4 hb = {(bf16)hn.x, (bf16)hn.y, (bf16)hn.z, (bf16)hn.w};
    ((bf16x4*)hnb)[idx] = hb;
}

// ---------------------------------------------------------------------------
extern "C" void kernel_launch(void* const* d_in, const int* in_sizes, int n_in,
                              void* d_out, int out_size, void* d_ws, size_t ws_size,
                              hipStream_t stream) {
    const float* sample   = (const float*)d_in[0];
    const float* hiddens  = (const float*)d_in[1];
    const float* mem_para = (const float*)d_in[2];
    const float* Wu = (const float*)d_in[3];
    const float* bu = (const float*)d_in[4];
    const float* Wr = (const float*)d_in[5];
    const float* br = (const float*)d_in[6];
    const float* Wm = (const float*)d_in[7];
    const float* bm = (const float*)d_in[8];
    const float* Wh = (const float*)d_in[9];
    const float* bh = (const float*)d_in[10];
    const float* Wo = (const float*)d_in[11];
    const float* bo = (const float*)d_in[12];

    float* out        = (float*)d_out;
    float* out_output = out;                                  // [B,512]
    float* out_upd    = out + SLICE;                          // [16,B,512]
    float* out_mg     = out + SLICE + (size_t)NSTEP * SLICE;  // [B,512]

    const float* hidden = hiddens + (size_t)(NSTEP - 1) * SLICE;

    // workspace layout; 4MB-aligned chunks
    char* ws = (char*)d_ws;
    bf16* Sb    = (bf16*)(ws);                          // sample bf16
    bf16* Hb    = (bf16*)(ws + (((size_t) 4) << 20));   // hidden bf16
    bf16* Mb    = (bf16*)(ws + (((size_t) 8) << 20));   // mem_para bf16
    bf16* RHb   = (bf16*)(ws + (((size_t)12) << 20));   // reset_gate*hidden
    bf16* HNb   = (bf16*)(ws + (((size_t)16) << 20));   // hidden_now
    bf16* UGb   = (bf16*)(ws + (((size_t)20) << 20));   // update_gate
    bf16* HTb   = (bf16*)(ws + (((size_t)24) << 20));   // h_tilde
    bf16* Wall_t = (bf16*)(ws + (((size_t)28) << 20));  // [1536][1536] (4.5MB)
    bf16* Wh_t  = (bf16*)(ws + (((size_t)33) << 20));   // [512][1024]
    bf16* Wo_t  = (bf16*)(ws + (((size_t)35) << 20));   // [512][512]

    dim3 blk(256);
    const int n4 = SLICE / 4;

    // 1. prep: converts + Wall_t pad-zero (6400 blocks)
    prep_data<<<6400, blk, 0, stream>>>(sample, hidden, mem_para, Sb, Hb, Mb, Wall_t);
    // 2. prep: all weight transposes (2560 tiles)
    prep_weights<<<2560, blk, 0, stream>>>(Wu, Wr, Wm, Wh, Wo, Wall_t, Wh_t, Wo_t);

    // 3. fused U|R|M gates: N=1536, K=1536 (Wu/Wr zero-padded over mem_para seg)
    gemm_mfma<0, 24><<<dim3(32, 24), blk, 0, stream>>>(
        Sb, Hb, Mb, Wall_t, 1536, bu, br, bm, UGb, RHb, out_mg, Hb);
    // 4. h_tilde = tanh([sample, rh] @ Wh + bh): N=512, K=1024
    gemm_mfma<2, 16><<<dim3(32, 8), blk, 0, stream>>>(
        Sb, RHb, nullptr, Wh_t, 1024, bh, nullptr, nullptr, HTb, nullptr, nullptr, nullptr);
    // 5. filter + shifted copy + hidden_now
    filter_combine<<<n4 / 256, blk, 0, stream>>>(hiddens, UGb, HTb, out_mg, out_upd, HNb);
    // 6. output = hidden_now @ Wo + bo: N=512, K=512
    gemm_mfma<3, 8><<<dim3(32, 8), blk, 0, stream>>>(
        HNb, nullptr, nullptr, Wo_t, 512, bo, nullptr, nullptr, out_output, nullptr, nullptr, nullptr);
}